// Round 10
// baseline (166.136 us; speedup 1.0000x reference)
//
#include <hip/hip_runtime.h>

#define B_ 16
#define C_ 256
#define N_ 1024
#define NH 8
#define HD 32
#define KD 16
#define QKV_OUT_ 512
#define BN_EPS 1e-3f
// softmax scale * log2(e), pre-folded into the q-channel weights
#define SCALE2_ (0.25f * 1.44269504088896f)

typedef __attribute__((ext_vector_type(8))) short short8;
typedef __attribute__((ext_vector_type(16))) float float16;

__device__ inline unsigned short f2bf(float f) {
  unsigned int u = __float_as_uint(f);
  return (unsigned short)((u + 0x7FFF + ((u >> 16) & 1)) >> 16);  // RNE
}
__device__ inline float bf2f(unsigned short s) {
  return __uint_as_float(((unsigned int)s) << 16);
}
__device__ inline float16 zero16() {
  float16 z;
  #pragma unroll
  for (int i = 0; i < 16; ++i) z[i] = 0.f;
  return z;
}
__device__ inline unsigned int pack_bf16_trunc(float a, float b) {
  return __builtin_amdgcn_perm(__float_as_uint(b), __float_as_uint(a), 0x07060302u);
}
__device__ inline unsigned int pack_bf16_rne(float a, float b) {
  return (unsigned int)f2bf(a) | ((unsigned int)f2bf(b) << 16);
}
__device__ inline float fast_exp2(float x) {
#if __has_builtin(__builtin_amdgcn_exp2f)
  return __builtin_amdgcn_exp2f(x);
#else
  return exp2f(x);
#endif
}
// permlane32_swap: a' = {a.lo, b.lo}, b' = {a.hi, b.hi}
__device__ inline void pl32(unsigned int& a, unsigned int& b) {
#if __has_builtin(__builtin_amdgcn_permlane32_swap)
  typedef __attribute__((ext_vector_type(2))) int int2v;
  int2v r = __builtin_amdgcn_permlane32_swap((int)a, (int)b, false, false);
  a = (unsigned int)r[0];
  b = (unsigned int)r[1];
#else
  unsigned int ea = (unsigned int)__shfl_xor((int)a, 32, 64);
  unsigned int eb = (unsigned int)__shfl_xor((int)b, 32, 64);
  bool hi = (threadIdx.x & 32) != 0;
  unsigned int an = hi ? eb : a;
  unsigned int bn = hi ? b : ea;
  a = an; b = bn;
#endif
}
__device__ inline short8 lds_frag(const unsigned short* p) {
  union { uint2 u[2]; short8 s; } r;
  r.u[0] = *(const uint2*)p;
  r.u[1] = *(const uint2*)(p + 4);
  return r.s;
}
__device__ inline void lds_store16(unsigned short* p, uint4 v) {
  *(uint2*)p = make_uint2(v.x, v.y);
  *(uint2*)(p + 4) = make_uint2(v.z, v.w);
}
// async global->LDS, 16B/lane: HW writes lds_base + lane*16 (wave-uniform base)
__device__ inline void gl2lds16(const unsigned short* g, unsigned short* l) {
#if __has_builtin(__builtin_amdgcn_global_load_lds)
  __builtin_amdgcn_global_load_lds(
      (const __attribute__((address_space(1))) unsigned int*)g,
      (__attribute__((address_space(3))) unsigned int*)l, 16, 0, 0);
#else
  const int lane = threadIdx.x & 63;
  *(uint4*)((char*)l + lane * 16) = *(const uint4*)g;
#endif
}

// ---------------------------------------------------------------------------
// Fold BN into conv weights (bf16) + bias.  q-channels (o%64 < 16) also get
// SCALE2_ folded so attention uses raw exp2 with no Q repack.
// ---------------------------------------------------------------------------
__global__ __launch_bounds__(256) void fold_weights(
    const float* __restrict__ qkv_w, const float* __restrict__ qg,
    const float* __restrict__ qb, const float* __restrict__ qm,
    const float* __restrict__ qv,
    const float* __restrict__ proj_w, const float* __restrict__ pg,
    const float* __restrict__ pb, const float* __restrict__ pm,
    const float* __restrict__ pv,
    unsigned short* __restrict__ wq, float* __restrict__ biasq,
    unsigned short* __restrict__ wp, float* __restrict__ biasp)
{
  const int o = blockIdx.x, c = threadIdx.x;
  if (o < QKV_OUT_) {
    float s = ((o & 63) < 16) ? SCALE2_ : 1.f;
    float inv = qg[o] * rsqrtf(qv[o] + BN_EPS) * s;
    wq[o * C_ + c] = f2bf(qkv_w[o * C_ + c] * inv);
    if (c == 0) biasq[o] = qb[o] * s - qm[o] * inv;
  } else {
    int oo = o - QKV_OUT_;
    float inv = pg[oo] * rsqrtf(pv[oo] + BN_EPS);
    wp[oo * C_ + c] = f2bf(proj_w[oo * C_ + c] * inv);
    if (c == 0) biasp[oo] = pb[oo] - pm[oo] * inv;
  }
}

// ---------------------------------------------------------------------------
// qkv GEMM, 64(o=1 head) x 128(tok) tile, BK=64, grid (b*8 ntiles, 8 heads)
// = 1024 blocks (4/CU).  W staged via global_load_lds (no VALU); B staged
// from planar f32 x via coalesced scalar loads + bf16 pack (fused transpose).
// Epilogue: q,k -> token-major qkT[b][h][token][32]; v -> planar bf16 vbuf.
// ---------------------------------------------------------------------------
__global__ __launch_bounds__(256) void gemm_qkv(
    const float* __restrict__ x, const unsigned short* __restrict__ wq,
    const float* __restrict__ bias,
    unsigned short* __restrict__ qkT, unsigned short* __restrict__ vbuf)
{
  __shared__ __align__(16) unsigned short wa[64 * 64];   // [o-row][ch]  8 KB
  __shared__ __align__(16) unsigned short xb[128 * 64];  // [token][ch] 16 KB
  const int tid = threadIdx.x;
  const int wave = tid >> 6, lane = tid & 63, l31 = lane & 31, lh = lane >> 5;
  const int wm = wave & 1, wn = wave >> 1;
  const int b = blockIdx.x >> 3, nloc = (blockIdx.x & 7) * 128;
  const int hh = blockIdx.y;
  const int o0 = hh * 64;

  const int tok = tid & 127, ch0 = (tid >> 7) * 32;
  const float* xcol = x + (size_t)b * C_ * N_ + nloc + tok;

  float16 acc[2];
  acc[0] = zero16(); acc[1] = zero16();

  for (int kc = 0; kc < 4; ++kc) {
    __syncthreads();  // prior step's fragment reads complete
    // W: 2 DMA rounds/wave (8 rows of 128B each)
    #pragma unroll
    for (int j = 0; j < 2; ++j) {
      const int rbase = wave * 16 + j * 8;
      gl2lds16(wq + (size_t)(o0 + rbase + (lane >> 3)) * C_ + kc * 64 + (lane & 7) * 8,
               &wa[rbase * 64]);
    }
    // B: fused transpose staging (32 coalesced f32 loads / thread)
    float xv[32];
    #pragma unroll
    for (int j = 0; j < 32; ++j)
      xv[j] = xcol[(size_t)(kc * 64 + ch0 + j) * N_];
    unsigned int pk[16];
    #pragma unroll
    for (int q = 0; q < 16; ++q) pk[q] = pack_bf16_rne(xv[2 * q], xv[2 * q + 1]);
    #pragma unroll
    for (int s = 0; s < 4; ++s)
      *(uint4*)&xb[tok * 64 + ch0 + s * 8] =
          make_uint4(pk[4 * s], pk[4 * s + 1], pk[4 * s + 2], pk[4 * s + 3]);
    __syncthreads();  // DMA vmcnt drain + staging visible

    #pragma unroll
    for (int ks = 0; ks < 4; ++ks) {
      const int ko = ks * 16 + lh * 8;
      short8 a0 = *(const short8*)&wa[(wm * 32 + l31) * 64 + ko];
      short8 b0 = *(const short8*)&xb[(wn * 64 + l31) * 64 + ko];
      short8 b1 = *(const short8*)&xb[(wn * 64 + 32 + l31) * 64 + ko];
      acc[0] = __builtin_amdgcn_mfma_f32_32x32x16_bf16(a0, b0, acc[0], 0, 0, 0);
      acc[1] = __builtin_amdgcn_mfma_f32_32x32x16_bf16(a0, b1, acc[1], 0, 0, 0);
    }
  }

  if (wm == 0) {
    // q+k channels (cc 0..31) -> token-major qkT[b][hh][token][cc]
    #pragma unroll
    for (int bn = 0; bn < 2; ++bn) {
      int n = nloc + wn * 64 + bn * 32 + l31;
      unsigned short* row = qkT + (((size_t)b * NH + hh) * N_ + n) * 32;
      #pragma unroll
      for (int qd = 0; qd < 4; ++qd) {
        int cc0 = 8 * qd + 4 * lh;
        ushort4 rv;
        rv.x = f2bf(acc[bn][4 * qd + 0] + bias[hh * 64 + cc0 + 0]);
        rv.y = f2bf(acc[bn][4 * qd + 1] + bias[hh * 64 + cc0 + 1]);
        rv.z = f2bf(acc[bn][4 * qd + 2] + bias[hh * 64 + cc0 + 2]);
        rv.w = f2bf(acc[bn][4 * qd + 3] + bias[hh * 64 + cc0 + 3]);
        *(ushort4*)(row + cc0) = rv;
      }
    }
  } else {
    // v channels -> planar bf16 vbuf[b][hh*32+d][n]
    #pragma unroll
    for (int r = 0; r < 16; ++r) {
      int d = (r & 3) + 8 * (r >> 2) + 4 * lh;
      float bo = bias[hh * 64 + 32 + d];
      unsigned short* vrow =
          vbuf + ((size_t)b * C_ + hh * 32 + d) * N_ + nloc + wn * 64 + l31;
      #pragma unroll
      for (int bn = 0; bn < 2; ++bn)
        vrow[bn * 32] = f2bf(acc[bn][r] + bo);
    }
  }
}

// ---------------------------------------------------------------------------
// proj GEMM, 64(o) x 128(tok) tile, BK=64, grid (128 ntiles, 4 otiles) = 512
// blocks (2/CU).  Both operands staged via global_load_lds.  f32 planar out.
// ---------------------------------------------------------------------------
__global__ __launch_bounds__(256) void gemm_proj(
    const unsigned short* __restrict__ inT, const unsigned short* __restrict__ wp,
    const float* __restrict__ bias, float* __restrict__ outf)
{
  __shared__ __align__(16) unsigned short wa[64 * 64];   //  8 KB
  __shared__ __align__(16) unsigned short xb[128 * 64];  // 16 KB
  const int tid = threadIdx.x;
  const int wave = tid >> 6, lane = tid & 63, l31 = lane & 31, lh = lane >> 5;
  const int wm = wave & 1, wn = wave >> 1;
  const int n0g = blockIdx.x * 128;
  const int o0 = blockIdx.y * 64;
  const int b = n0g >> 10, nloc = n0g & 1023;

  float16 acc[2];
  acc[0] = zero16(); acc[1] = zero16();

  for (int kc = 0; kc < 4; ++kc) {
    __syncthreads();
    #pragma unroll
    for (int j = 0; j < 2; ++j) {
      const int rbase = wave * 16 + j * 8;
      gl2lds16(wp + (size_t)(o0 + rbase + (lane >> 3)) * C_ + kc * 64 + (lane & 7) * 8,
               &wa[rbase * 64]);
    }
    #pragma unroll
    for (int j = 0; j < 4; ++j) {
      const int rbase = wave * 32 + j * 8;
      gl2lds16(inT + (size_t)(n0g + rbase + (lane >> 3)) * C_ + kc * 64 + (lane & 7) * 8,
               &xb[rbase * 64]);
    }
    __syncthreads();

    #pragma unroll
    for (int ks = 0; ks < 4; ++ks) {
      const int ko = ks * 16 + lh * 8;
      short8 a0 = *(const short8*)&wa[(wm * 32 + l31) * 64 + ko];
      short8 b0 = *(const short8*)&xb[(wn * 64 + l31) * 64 + ko];
      short8 b1 = *(const short8*)&xb[(wn * 64 + 32 + l31) * 64 + ko];
      acc[0] = __builtin_amdgcn_mfma_f32_32x32x16_bf16(a0, b0, acc[0], 0, 0, 0);
      acc[1] = __builtin_amdgcn_mfma_f32_32x32x16_bf16(a0, b1, acc[1], 0, 0, 0);
    }
  }

  #pragma unroll
  for (int r = 0; r < 16; ++r) {
    int o = o0 + wm * 32 + (r & 3) + 8 * (r >> 2) + 4 * lh;
    float bo = bias[o];
    float* orow = outf + ((size_t)b * C_ + o) * N_ + nloc + wn * 64 + l31;
    #pragma unroll
    for (int bn = 0; bn < 2; ++bn)
      orow[bn * 32] = acc[bn][r] + bo;
  }
}

// ---------------------------------------------------------------------------
// depthwise 3x3 + BN on v (bf16 planar) -> posenc bf16 planar.
// ---------------------------------------------------------------------------
__global__ __launch_bounds__(256) void dwconv_bn(
    const unsigned short* __restrict__ vbuf, const float* __restrict__ pw,
    const float* __restrict__ gamma, const float* __restrict__ beta,
    const float* __restrict__ mean, const float* __restrict__ var,
    unsigned short* __restrict__ posb)
{
  __shared__ float t[34][34];
  const int c = blockIdx.x, b = blockIdx.y;
  const int tid = threadIdx.x;
  const unsigned short* vp = vbuf + ((size_t)b * C_ + c) * N_;

  #pragma unroll
  for (int r = 0; r < 4; ++r) {
    int idx = r * 256 + tid;
    t[(idx >> 5) + 1][(idx & 31) + 1] = bf2f(vp[idx]);
  }
  if (tid < 34) {
    t[0][tid] = 0.f; t[33][tid] = 0.f;
    t[tid][0] = 0.f; t[tid][33] = 0.f;
  }
  __syncthreads();

  float w9[9];
  #pragma unroll
  for (int i = 0; i < 9; ++i) w9[i] = pw[c * 9 + i];
  float inv = gamma[c] * rsqrtf(var[c] + BN_EPS);
  float add = beta[c] - mean[c] * inv;

  unsigned short* op = posb + ((size_t)b * C_ + c) * N_;
  #pragma unroll
  for (int r = 0; r < 4; ++r) {
    int idx = r * 256 + tid;
    int y = idx >> 5, x = idx & 31;
    float s = 0.f;
    #pragma unroll
    for (int dy = 0; dy < 3; ++dy)
      #pragma unroll
      for (int dx = 0; dx < 3; ++dx)
        s += t[y + dy][x + dx] * w9[dy * 3 + dx];
    op[idx] = f2bf(s * inv + add);
  }
}

// ---------------------------------------------------------------------------
// MFMA attention: 32 q/wave, grid (bh, qt) XCD-affine, LDS K/V double-
// buffered with reg-prefetch, conflict-free strides, permlane32_swap
// P-transpose, DUAL PV accumulators (halved dependent-MFMA chain),
// posenc fused, token-major bf16 out.
// ---------------------------------------------------------------------------
__global__ __launch_bounds__(256) void attn_mfma(
    const unsigned short* __restrict__ qkT, const unsigned short* __restrict__ vbuf,
    const unsigned short* __restrict__ posb, unsigned short* __restrict__ vattnT)
{
  __shared__ __align__(8) unsigned short k_lds[2][128 * 28];
  __shared__ __align__(8) unsigned short v_lds[2][32 * 140];

  const int tid = threadIdx.x;
  const int wave = tid >> 6, lane = tid & 63;
  const int l31 = lane & 31, lh = lane >> 5;
  const int b = blockIdx.x >> 3, h = blockIdx.x & 7;
  const int qbase = blockIdx.y * 128 + wave * 32;

  const unsigned short* qkb = qkT + ((size_t)b * NH + h) * N_ * 32;
  const unsigned short* vhead = vbuf + ((size_t)b * C_ + h * HD) * N_;

  const int skey = tid >> 1, shalf = tid & 1;
  const int svd = tid >> 3, svseg = tid & 7;

  short8 qf = lds_frag(qkb + (size_t)(qbase + l31) * 32 + lh * 8);

  uint4 gk, gv0, gv1;
  auto loadc = [&](int kc) {
    gk  = *(const uint4*)(qkb + (size_t)(kc + skey) * 32 + 16 + shalf * 8);
    gv0 = *(const uint4*)(vhead + (size_t)svd * N_ + kc + svseg * 16);
    gv1 = *(const uint4*)(vhead + (size_t)svd * N_ + kc + svseg * 16 + 8);
  };
  auto storec = [&](int bufi) {
    lds_store16(&k_lds[bufi][skey * 28 + shalf * 8], gk);
    lds_store16(&v_lds[bufi][svd * 140 + svseg * 16], gv0);
    lds_store16(&v_lds[bufi][svd * 140 + svseg * 16 + 8], gv1);
  };

  loadc(0);
  storec(0);
  __syncthreads();

  float16 oaccE = zero16(), oaccO = zero16();
  float ls[4] = {0.f, 0.f, 0.f, 0.f};

  for (int c = 0; c < 8; ++c) {
    const int buf = c & 1;
    if (c < 7) loadc((c + 1) * 128);

    #pragma unroll
    for (int t = 0; t < 4; ++t) {
      const int key0 = t * 32;
      short8 kf = lds_frag(&k_lds[buf][(key0 + l31) * 28 + lh * 8]);
      float16 st = __builtin_amdgcn_mfma_f32_32x32x16_bf16(kf, qf, zero16(), 0, 0, 0);

      unsigned int u[8];
      #pragma unroll
      for (int q = 0; q < 8; ++q) {
        float pe = fast_exp2(st[2 * q]);
        float po = fast_exp2(st[2 * q + 1]);
        ls[q & 3] += pe + po;
        u[q] = pack_bf16_trunc(pe, po);
      }

      #pragma unroll
      for (int f = 0; f < 2; ++f) {
        short8 vf = lds_frag(&v_lds[buf][l31 * 140 + key0 + f * 16 + lh * 8]);
        const int q0 = f * 4;
        unsigned int a0 = u[q0], a2 = u[q0 + 2]; pl32(a0, a2);
        unsigned int a1 = u[q0 + 1], a3 = u[q0 + 3]; pl32(a1, a3);
        union { unsigned int w[4]; short8 s; } bf;
        bf.w[0] = a0; bf.w[1] = a1; bf.w[2] = a2; bf.w[3] = a3;
        if (f == 0)
          oaccE = __builtin_amdgcn_mfma_f32_32x32x16_bf16(vf, bf.s, oaccE, 0, 0, 0);
        else
          oaccO = __builtin_amdgcn_mfma_f32_32x32x16_bf16(vf, bf.s, oaccO, 0, 0, 0);
      }
    }

    if (c < 7) storec(buf ^ 1);
    __syncthreads();
  }

  float lsum = (ls[0] + ls[1]) + (ls[2] + ls[3]);
  lsum += __shfl_xor(lsum, 32, 64);
  const float linv = 1.f / lsum;

  const int token = qbase + l31;
  float val[16];
  #pragma unroll
  for (int r = 0; r < 16; ++r) {
    int d = (r & 3) + 8 * (r >> 2) + 4 * lh;
    val[r] = (oaccE[r] + oaccO[r]) * linv +
             bf2f(posb[((size_t)b * C_ + h * HD + d) * N_ + token]);
  }
  unsigned int u[8];
  #pragma unroll
  for (int m = 0; m < 8; ++m) u[m] = pack_bf16_rne(val[2 * m], val[2 * m + 1]);
  pl32(u[0], u[4]); pl32(u[1], u[5]); pl32(u[2], u[6]); pl32(u[3], u[7]);
  unsigned short* row = vattnT + ((size_t)b * N_ + token) * C_ + h * HD + lh * 16;
  *(uint4*)(row)     = make_uint4(u[0], u[1], u[4], u[5]);
  *(uint4*)(row + 8) = make_uint4(u[2], u[3], u[6], u[7]);
}

// ---------------------------------------------------------------------------
extern "C" void kernel_launch(void* const* d_in, const int* in_sizes, int n_in,
                              void* d_out, int out_size, void* d_ws, size_t ws_size,
                              hipStream_t stream) {
  const float* x          = (const float*)d_in[0];
  const float* qkv_w      = (const float*)d_in[1];
  const float* qkv_gamma  = (const float*)d_in[2];
  const float* qkv_beta   = (const float*)d_in[3];
  const float* qkv_mean   = (const float*)d_in[4];
  const float* qkv_var    = (const float*)d_in[5];
  const float* pe_w       = (const float*)d_in[6];
  const float* pe_gamma   = (const float*)d_in[7];
  const float* pe_beta    = (const float*)d_in[8];
  const float* pe_mean    = (const float*)d_in[9];
  const float* pe_var     = (const float*)d_in[10];
  const float* proj_w     = (const float*)d_in[11];
  const float* proj_gamma = (const float*)d_in[12];
  const float* proj_beta  = (const float*)d_in[13];
  const float* proj_mean  = (const float*)d_in[14];
  const float* proj_var   = (const float*)d_in[15];
  float* out = (float*)d_out;

  char* ws = (char*)d_ws;
  unsigned short* qkT = (unsigned short*)ws;
  ws += (size_t)B_ * NH * N_ * 32 * sizeof(unsigned short);
  unsigned short* vbuf = (unsigned short*)ws;
  ws += (size_t)B_ * C_ * N_ * sizeof(unsigned short);
  unsigned short* vattnT = (unsigned short*)ws;
  ws += (size_t)B_ * N_ * C_ * sizeof(unsigned short);
  unsigned short* posb = (unsigned short*)ws;
  ws += (size_t)B_ * C_ * N_ * sizeof(unsigned short);
  unsigned short* wq = (unsigned short*)ws;
  ws += (size_t)QKV_OUT_ * C_ * sizeof(unsigned short);
  unsigned short* wp = (unsigned short*)ws;
  ws += (size_t)C_ * C_ * sizeof(unsigned short);
  float* biasq = (float*)ws; ws += QKV_OUT_ * sizeof(float);
  float* biasp = (float*)ws;

  fold_weights<<<dim3(QKV_OUT_ + C_), 256, 0, stream>>>(
      qkv_w, qkv_gamma, qkv_beta, qkv_mean, qkv_var,
      proj_w, proj_gamma, proj_beta, proj_mean, proj_var,
      wq, biasq, wp, biasp);

  // qkv GEMM (fused transpose, 1 head/block): grid (b*ntile, head)
  gemm_qkv<<<dim3(128, 8), 256, 0, stream>>>(x, wq, biasq, qkT, vbuf);

  dwconv_bn<<<dim3(C_, B_), 256, 0, stream>>>(
      vbuf, pe_w, pe_gamma, pe_beta, pe_mean, pe_var, posb);

  // attention: grid.x = bh (XCD affinity), grid.y = q-tile
  attn_mfma<<<dim3(128, 8), 256, 0, stream>>>(qkT, vbuf, posb, vattnT);

  // proj GEMM: grid (b*ntile, otile)
  gemm_proj<<<dim3(128, 4), 256, 0, stream>>>(vattnT, wp, biasp, out);
}

// Round 11
// 155.878 us; speedup vs baseline: 1.0658x; 1.0658x over previous
//
#include <hip/hip_runtime.h>

#define B_ 16
#define C_ 256
#define N_ 1024
#define NH 8
#define HD 32
#define KD 16
#define QKV_OUT_ 512
#define BN_EPS 1e-3f
// softmax scale * log2(e), pre-folded into the q-channel weights
#define SCALE2_ (0.25f * 1.44269504088896f)

typedef __attribute__((ext_vector_type(8))) short short8;
typedef __attribute__((ext_vector_type(16))) float float16;

__device__ inline unsigned short f2bf(float f) {
  unsigned int u = __float_as_uint(f);
  return (unsigned short)((u + 0x7FFF + ((u >> 16) & 1)) >> 16);  // RNE
}
__device__ inline float bf2f(unsigned short s) {
  return __uint_as_float(((unsigned int)s) << 16);
}
__device__ inline float16 zero16() {
  float16 z;
  #pragma unroll
  for (int i = 0; i < 16; ++i) z[i] = 0.f;
  return z;
}
__device__ inline unsigned int pack_bf16_trunc(float a, float b) {
  return __builtin_amdgcn_perm(__float_as_uint(b), __float_as_uint(a), 0x07060302u);
}
__device__ inline unsigned int pack_bf16_rne(float a, float b) {
  return (unsigned int)f2bf(a) | ((unsigned int)f2bf(b) << 16);
}
__device__ inline float fast_exp2(float x) {
#if __has_builtin(__builtin_amdgcn_exp2f)
  return __builtin_amdgcn_exp2f(x);
#else
  return exp2f(x);
#endif
}
// permlane32_swap: a' = {a.lo, b.lo}, b' = {a.hi, b.hi}
__device__ inline void pl32(unsigned int& a, unsigned int& b) {
#if __has_builtin(__builtin_amdgcn_permlane32_swap)
  typedef __attribute__((ext_vector_type(2))) int int2v;
  int2v r = __builtin_amdgcn_permlane32_swap((int)a, (int)b, false, false);
  a = (unsigned int)r[0];
  b = (unsigned int)r[1];
#else
  unsigned int ea = (unsigned int)__shfl_xor((int)a, 32, 64);
  unsigned int eb = (unsigned int)__shfl_xor((int)b, 32, 64);
  bool hi = (threadIdx.x & 32) != 0;
  unsigned int an = hi ? eb : a;
  unsigned int bn = hi ? b : ea;
  a = an; b = bn;
#endif
}
__device__ inline short8 lds_frag(const unsigned short* p) {
  union { uint2 u[2]; short8 s; } r;
  r.u[0] = *(const uint2*)p;
  r.u[1] = *(const uint2*)(p + 4);
  return r.s;
}
__device__ inline void lds_store16(unsigned short* p, uint4 v) {
  *(uint2*)p = make_uint2(v.x, v.y);
  *(uint2*)(p + 4) = make_uint2(v.z, v.w);
}

// ---------------------------------------------------------------------------
// Fold BN into conv weights (bf16) + bias.  q-channels (o%64 < 16) also get
// SCALE2_ folded so attention uses raw exp2 with no Q repack.
// ---------------------------------------------------------------------------
__global__ __launch_bounds__(256) void fold_weights(
    const float* __restrict__ qkv_w, const float* __restrict__ qg,
    const float* __restrict__ qb, const float* __restrict__ qm,
    const float* __restrict__ qv,
    const float* __restrict__ proj_w, const float* __restrict__ pg,
    const float* __restrict__ pb, const float* __restrict__ pm,
    const float* __restrict__ pv,
    unsigned short* __restrict__ wq, float* __restrict__ biasq,
    unsigned short* __restrict__ wp, float* __restrict__ biasp)
{
  const int o = blockIdx.x, c = threadIdx.x;
  if (o < QKV_OUT_) {
    float s = ((o & 63) < 16) ? SCALE2_ : 1.f;
    float inv = qg[o] * rsqrtf(qv[o] + BN_EPS) * s;
    wq[o * C_ + c] = f2bf(qkv_w[o * C_ + c] * inv);
    if (c == 0) biasq[o] = qb[o] * s - qm[o] * inv;
  } else {
    int oo = o - QKV_OUT_;
    float inv = pg[oo] * rsqrtf(pv[oo] + BN_EPS);
    wp[oo * C_ + c] = f2bf(proj_w[oo * C_ + c] * inv);
    if (c == 0) biasp[oo] = pb[oo] - pm[oo] * inv;
  }
}

// ---------------------------------------------------------------------------
// qkv GEMM (R8 version, unchanged — best measured): fused x transpose,
// tile 128(o) x 128(tok), BK=32, double-buffered LDS stride 44 shorts
// (2-way bank aliasing = free), reg-prefetch, 1 barrier per K-step.
// Epilogue: q,k -> token-major qkT[b][h][token][32]; v -> planar bf16 vbuf.
// ---------------------------------------------------------------------------
__global__ __launch_bounds__(256) void gemm_qkv(
    const float* __restrict__ x, const unsigned short* __restrict__ wq,
    const float* __restrict__ bias,
    unsigned short* __restrict__ qkT, unsigned short* __restrict__ vbuf)
{
  constexpr int STR = 44;
  __shared__ __align__(8) unsigned short wa[2][128 * STR];
  __shared__ __align__(8) unsigned short xb[2][128 * STR];
  const int tid = threadIdx.x;
  const int wave = tid >> 6, lane = tid & 63, l31 = lane & 31, lh = lane >> 5;
  const int wm = wave & 1, wn = wave >> 1;
  const int b = blockIdx.x >> 3, nloc = (blockIdx.x & 7) * 128;
  const int o0 = blockIdx.y * 128;

  // A staging: 512 slots of 16B; thread covers slots tid, tid+256
  const int r0 = tid >> 2, oc0 = (tid & 3) * 8;
  const int r1 = r0 + 64;
  // B staging: token tok, channel half chalf (16 ch), 16 scalar f32 loads
  const int tok = tid & 127, chalf = (tid >> 7) * 16;
  const float* xbase = x + (size_t)b * C_ * N_ + nloc + tok;

  uint4 ga0, ga1;
  float nb[16];

  auto loadk = [&](int kc) {
    ga0 = *(const uint4*)(wq + (size_t)(o0 + r0) * C_ + kc * 32 + oc0);
    ga1 = *(const uint4*)(wq + (size_t)(o0 + r1) * C_ + kc * 32 + oc0);
    #pragma unroll
    for (int j = 0; j < 16; ++j)
      nb[j] = xbase[(size_t)(kc * 32 + chalf + j) * N_];
  };
  auto storek = [&](int bufi) {
    lds_store16(&wa[bufi][r0 * STR + oc0], ga0);
    lds_store16(&wa[bufi][r1 * STR + oc0], ga1);
    unsigned int pk[8];
    #pragma unroll
    for (int q = 0; q < 8; ++q) pk[q] = pack_bf16_rne(nb[2 * q], nb[2 * q + 1]);
    lds_store16(&xb[bufi][tok * STR + chalf], make_uint4(pk[0], pk[1], pk[2], pk[3]));
    lds_store16(&xb[bufi][tok * STR + chalf + 8], make_uint4(pk[4], pk[5], pk[6], pk[7]));
  };

  float16 acc[2][2];
  #pragma unroll
  for (int i = 0; i < 2; ++i)
    #pragma unroll
    for (int j = 0; j < 2; ++j) acc[i][j] = zero16();

  loadk(0);
  storek(0);
  __syncthreads();

  for (int kc = 0; kc < 8; ++kc) {
    const int buf = kc & 1;
    if (kc < 7) loadk(kc + 1);   // global loads land during MFMA

    #pragma unroll
    for (int ks = 0; ks < 2; ++ks) {
      const int ko = ks * 16 + lh * 8;
      short8 a0 = lds_frag(&wa[buf][(wm * 64 + l31) * STR + ko]);
      short8 a1 = lds_frag(&wa[buf][(wm * 64 + 32 + l31) * STR + ko]);
      short8 b0 = lds_frag(&xb[buf][(wn * 64 + l31) * STR + ko]);
      short8 b1 = lds_frag(&xb[buf][(wn * 64 + 32 + l31) * STR + ko]);
      acc[0][0] = __builtin_amdgcn_mfma_f32_32x32x16_bf16(a0, b0, acc[0][0], 0, 0, 0);
      acc[0][1] = __builtin_amdgcn_mfma_f32_32x32x16_bf16(a0, b1, acc[0][1], 0, 0, 0);
      acc[1][0] = __builtin_amdgcn_mfma_f32_32x32x16_bf16(a1, b0, acc[1][0], 0, 0, 0);
      acc[1][1] = __builtin_amdgcn_mfma_f32_32x32x16_bf16(a1, b1, acc[1][1], 0, 0, 0);
    }

    if (kc < 7) storek(buf ^ 1);
    __syncthreads();
  }

  const int hh = (o0 >> 6) + wm;  // o = o0 + wm*64 + am*32 + idx
  // am=0: q+k -> token-major qkT[b][hh][token][cc]
  #pragma unroll
  for (int bn = 0; bn < 2; ++bn) {
    int n = nloc + wn * 64 + bn * 32 + l31;
    unsigned short* row = qkT + (((size_t)b * NH + hh) * N_ + n) * 32;
    #pragma unroll
    for (int qd = 0; qd < 4; ++qd) {
      int cc0 = 8 * qd + 4 * lh;
      ushort4 rv;
      rv.x = f2bf(acc[0][bn][4 * qd + 0] + bias[hh * 64 + cc0 + 0]);
      rv.y = f2bf(acc[0][bn][4 * qd + 1] + bias[hh * 64 + cc0 + 1]);
      rv.z = f2bf(acc[0][bn][4 * qd + 2] + bias[hh * 64 + cc0 + 2]);
      rv.w = f2bf(acc[0][bn][4 * qd + 3] + bias[hh * 64 + cc0 + 3]);
      *(ushort4*)(row + cc0) = rv;
    }
  }
  // am=1: v -> planar bf16 vbuf[b][hh*32+d][n]
  #pragma unroll
  for (int r = 0; r < 16; ++r) {
    int d = (r & 3) + 8 * (r >> 2) + 4 * lh;
    float bo = bias[hh * 64 + 32 + d];
    unsigned short* vrow =
        vbuf + ((size_t)b * C_ + hh * 32 + d) * N_ + nloc + wn * 64 + l31;
    #pragma unroll
    for (int bn = 0; bn < 2; ++bn)
      vrow[bn * 32] = f2bf(acc[1][bn][r] + bo);
  }
}

// ---------------------------------------------------------------------------
// proj GEMM: 64(o) x 128(tok) tile (R8 had 128x128 at 1 block/CU — grid-
// starved).  Grid (128,4) = 512 blocks = 2/CU, LDS 34 KB.  Same double-
// buffered stride-44 pipeline, 1 barrier per K-step.  f32 planar out.
// ---------------------------------------------------------------------------
__global__ __launch_bounds__(256) void gemm_proj(
    const unsigned short* __restrict__ inT, const unsigned short* __restrict__ wp,
    const float* __restrict__ bias, float* __restrict__ outf)
{
  constexpr int STR = 44;
  __shared__ __align__(8) unsigned short wa[2][64 * STR];
  __shared__ __align__(8) unsigned short xb[2][128 * STR];
  const int tid = threadIdx.x;
  const int wave = tid >> 6, lane = tid & 63, l31 = lane & 31, lh = lane >> 5;
  const int wm = wave & 1, wn = wave >> 1;
  const int n0g = blockIdx.x * 128;
  const int o0 = blockIdx.y * 64;
  const int b = n0g >> 10, nloc = n0g & 1023;

  // A staging: 64 rows x 32 ch = 256 16B-slots (1/thread)
  const int ar = tid >> 2, aseg = (tid & 3) * 8;
  // B staging: 128 rows x 32 ch = 512 slots (2/thread: rows ar, ar+64)

  float16 acc[2];
  acc[0] = zero16(); acc[1] = zero16();

  uint4 ga, gb0, gb1;
  auto loadk = [&](int kc) {
    ga  = *(const uint4*)(wp + (size_t)(o0 + ar) * C_ + kc * 32 + aseg);
    gb0 = *(const uint4*)(inT + (size_t)(n0g + ar) * C_ + kc * 32 + aseg);
    gb1 = *(const uint4*)(inT + (size_t)(n0g + ar + 64) * C_ + kc * 32 + aseg);
  };
  auto storek = [&](int bufi) {
    lds_store16(&wa[bufi][ar * STR + aseg], ga);
    lds_store16(&xb[bufi][ar * STR + aseg], gb0);
    lds_store16(&xb[bufi][(ar + 64) * STR + aseg], gb1);
  };

  loadk(0);
  storek(0);
  __syncthreads();

  for (int kc = 0; kc < 8; ++kc) {
    const int buf = kc & 1;
    if (kc < 7) loadk(kc + 1);

    #pragma unroll
    for (int ks = 0; ks < 2; ++ks) {
      const int ko = ks * 16 + lh * 8;
      short8 a0 = lds_frag(&wa[buf][(wm * 32 + l31) * STR + ko]);
      short8 b0 = lds_frag(&xb[buf][(wn * 64 + l31) * STR + ko]);
      short8 b1 = lds_frag(&xb[buf][(wn * 64 + 32 + l31) * STR + ko]);
      acc[0] = __builtin_amdgcn_mfma_f32_32x32x16_bf16(a0, b0, acc[0], 0, 0, 0);
      acc[1] = __builtin_amdgcn_mfma_f32_32x32x16_bf16(a0, b1, acc[1], 0, 0, 0);
    }

    if (kc < 7) storek(buf ^ 1);
    __syncthreads();
  }

  #pragma unroll
  for (int r = 0; r < 16; ++r) {
    int o = o0 + wm * 32 + (r & 3) + 8 * (r >> 2) + 4 * lh;
    float bo = bias[o];
    float* orow = outf + ((size_t)b * C_ + o) * N_ + nloc + wn * 64 + l31;
    #pragma unroll
    for (int bn = 0; bn < 2; ++bn)
      orow[bn * 32] = acc[bn][r] + bo;
  }
}

// ---------------------------------------------------------------------------
// depthwise 3x3 + BN on v (bf16 planar) -> posenc bf16 planar.
// ---------------------------------------------------------------------------
__global__ __launch_bounds__(256) void dwconv_bn(
    const unsigned short* __restrict__ vbuf, const float* __restrict__ pw,
    const float* __restrict__ gamma, const float* __restrict__ beta,
    const float* __restrict__ mean, const float* __restrict__ var,
    unsigned short* __restrict__ posb)
{
  __shared__ float t[34][34];
  const int c = blockIdx.x, b = blockIdx.y;
  const int tid = threadIdx.x;
  const unsigned short* vp = vbuf + ((size_t)b * C_ + c) * N_;

  #pragma unroll
  for (int r = 0; r < 4; ++r) {
    int idx = r * 256 + tid;
    t[(idx >> 5) + 1][(idx & 31) + 1] = bf2f(vp[idx]);
  }
  if (tid < 34) {
    t[0][tid] = 0.f; t[33][tid] = 0.f;
    t[tid][0] = 0.f; t[tid][33] = 0.f;
  }
  __syncthreads();

  float w9[9];
  #pragma unroll
  for (int i = 0; i < 9; ++i) w9[i] = pw[c * 9 + i];
  float inv = gamma[c] * rsqrtf(var[c] + BN_EPS);
  float add = beta[c] - mean[c] * inv;

  unsigned short* op = posb + ((size_t)b * C_ + c) * N_;
  #pragma unroll
  for (int r = 0; r < 4; ++r) {
    int idx = r * 256 + tid;
    int y = idx >> 5, x = idx & 31;
    float s = 0.f;
    #pragma unroll
    for (int dy = 0; dy < 3; ++dy)
      #pragma unroll
      for (int dx = 0; dx < 3; ++dx)
        s += t[y + dy][x + dx] * w9[dy * 3 + dx];
    op[idx] = f2bf(s * inv + add);
  }
}

// ---------------------------------------------------------------------------
// MFMA attention: 32 q/wave, grid (bh, qt) XCD-affine, LDS K/V double-
// buffered with reg-prefetch, conflict-free strides, permlane32_swap
// P-transpose, DUAL PV accumulators (halved dependent-MFMA chain),
// posenc fused, token-major bf16 out.
// ---------------------------------------------------------------------------
__global__ __launch_bounds__(256) void attn_mfma(
    const unsigned short* __restrict__ qkT, const unsigned short* __restrict__ vbuf,
    const unsigned short* __restrict__ posb, unsigned short* __restrict__ vattnT)
{
  __shared__ __align__(8) unsigned short k_lds[2][128 * 28];
  __shared__ __align__(8) unsigned short v_lds[2][32 * 140];

  const int tid = threadIdx.x;
  const int wave = tid >> 6, lane = tid & 63;
  const int l31 = lane & 31, lh = lane >> 5;
  const int b = blockIdx.x >> 3, h = blockIdx.x & 7;
  const int qbase = blockIdx.y * 128 + wave * 32;

  const unsigned short* qkb = qkT + ((size_t)b * NH + h) * N_ * 32;
  const unsigned short* vhead = vbuf + ((size_t)b * C_ + h * HD) * N_;

  const int skey = tid >> 1, shalf = tid & 1;
  const int svd = tid >> 3, svseg = tid & 7;

  // Q fragment: 64B-aligned row -> single 16B load (scale pre-folded)
  short8 qf = *(const short8*)(qkb + (size_t)(qbase + l31) * 32 + lh * 8);

  uint4 gk, gv0, gv1;
  auto loadc = [&](int kc) {
    gk  = *(const uint4*)(qkb + (size_t)(kc + skey) * 32 + 16 + shalf * 8);
    gv0 = *(const uint4*)(vhead + (size_t)svd * N_ + kc + svseg * 16);
    gv1 = *(const uint4*)(vhead + (size_t)svd * N_ + kc + svseg * 16 + 8);
  };
  auto storec = [&](int bufi) {
    lds_store16(&k_lds[bufi][skey * 28 + shalf * 8], gk);
    lds_store16(&v_lds[bufi][svd * 140 + svseg * 16], gv0);
    lds_store16(&v_lds[bufi][svd * 140 + svseg * 16 + 8], gv1);
  };

  loadc(0);
  storec(0);
  __syncthreads();

  float16 oaccE = zero16(), oaccO = zero16();
  float ls[4] = {0.f, 0.f, 0.f, 0.f};

  for (int c = 0; c < 8; ++c) {
    const int buf = c & 1;
    if (c < 7) loadc((c + 1) * 128);

    #pragma unroll
    for (int t = 0; t < 4; ++t) {
      const int key0 = t * 32;
      short8 kf = lds_frag(&k_lds[buf][(key0 + l31) * 28 + lh * 8]);
      float16 st = __builtin_amdgcn_mfma_f32_32x32x16_bf16(kf, qf, zero16(), 0, 0, 0);

      unsigned int u[8];
      #pragma unroll
      for (int q = 0; q < 8; ++q) {
        float pe = fast_exp2(st[2 * q]);
        float po = fast_exp2(st[2 * q + 1]);
        ls[q & 3] += pe + po;
        u[q] = pack_bf16_trunc(pe, po);
      }

      #pragma unroll
      for (int f = 0; f < 2; ++f) {
        short8 vf = lds_frag(&v_lds[buf][l31 * 140 + key0 + f * 16 + lh * 8]);
        const int q0 = f * 4;
        unsigned int a0 = u[q0], a2 = u[q0 + 2]; pl32(a0, a2);
        unsigned int a1 = u[q0 + 1], a3 = u[q0 + 3]; pl32(a1, a3);
        union { unsigned int w[4]; short8 s; } bf;
        bf.w[0] = a0; bf.w[1] = a1; bf.w[2] = a2; bf.w[3] = a3;
        if (f == 0)
          oaccE = __builtin_amdgcn_mfma_f32_32x32x16_bf16(vf, bf.s, oaccE, 0, 0, 0);
        else
          oaccO = __builtin_amdgcn_mfma_f32_32x32x16_bf16(vf, bf.s, oaccO, 0, 0, 0);
      }
    }

    if (c < 7) storec(buf ^ 1);
    __syncthreads();
  }

  float lsum = (ls[0] + ls[1]) + (ls[2] + ls[3]);
  lsum += __shfl_xor(lsum, 32, 64);
  const float linv = 1.f / lsum;

  const int token = qbase + l31;
  float val[16];
  #pragma unroll
  for (int r = 0; r < 16; ++r) {
    int d = (r & 3) + 8 * (r >> 2) + 4 * lh;
    val[r] = (oaccE[r] + oaccO[r]) * linv +
             bf2f(posb[((size_t)b * C_ + h * HD + d) * N_ + token]);
  }
  unsigned int u[8];
  #pragma unroll
  for (int m = 0; m < 8; ++m) u[m] = pack_bf16_rne(val[2 * m], val[2 * m + 1]);
  pl32(u[0], u[4]); pl32(u[1], u[5]); pl32(u[2], u[6]); pl32(u[3], u[7]);
  unsigned short* row = vattnT + ((size_t)b * N_ + token) * C_ + h * HD + lh * 16;
  *(uint4*)(row)     = make_uint4(u[0], u[1], u[4], u[5]);
  *(uint4*)(row + 8) = make_uint4(u[2], u[3], u[6], u[7]);
}

// ---------------------------------------------------------------------------
extern "C" void kernel_launch(void* const* d_in, const int* in_sizes, int n_in,
                              void* d_out, int out_size, void* d_ws, size_t ws_size,
                              hipStream_t stream) {
  const float* x          = (const float*)d_in[0];
  const float* qkv_w      = (const float*)d_in[1];
  const float* qkv_gamma  = (const float*)d_in[2];
  const float* qkv_beta   = (const float*)d_in[3];
  const float* qkv_mean   = (const float*)d_in[4];
  const float* qkv_var    = (const float*)d_in[5];
  const float* pe_w       = (const float*)d_in[6];
  const float* pe_gamma   = (const float*)d_in[7];
  const float* pe_beta    = (const float*)d_in[8];
  const float* pe_mean    = (const float*)d_in[9];
  const float* pe_var     = (const float*)d_in[10];
  const float* proj_w     = (const float*)d_in[11];
  const float* proj_gamma = (const float*)d_in[12];
  const float* proj_beta  = (const float*)d_in[13];
  const float* proj_mean  = (const float*)d_in[14];
  const float* proj_var   = (const float*)d_in[15];
  float* out = (float*)d_out;

  char* ws = (char*)d_ws;
  unsigned short* qkT = (unsigned short*)ws;
  ws += (size_t)B_ * NH * N_ * 32 * sizeof(unsigned short);
  unsigned short* vbuf = (unsigned short*)ws;
  ws += (size_t)B_ * C_ * N_ * sizeof(unsigned short);
  unsigned short* vattnT = (unsigned short*)ws;
  ws += (size_t)B_ * N_ * C_ * sizeof(unsigned short);
  unsigned short* posb = (unsigned short*)ws;
  ws += (size_t)B_ * C_ * N_ * sizeof(unsigned short);
  unsigned short* wq = (unsigned short*)ws;
  ws += (size_t)QKV_OUT_ * C_ * sizeof(unsigned short);
  unsigned short* wp = (unsigned short*)ws;
  ws += (size_t)C_ * C_ * sizeof(unsigned short);
  float* biasq = (float*)ws; ws += QKV_OUT_ * sizeof(float);
  float* biasp = (float*)ws;

  fold_weights<<<dim3(QKV_OUT_ + C_), 256, 0, stream>>>(
      qkv_w, qkv_gamma, qkv_beta, qkv_mean, qkv_var,
      proj_w, proj_gamma, proj_beta, proj_mean, proj_var,
      wq, biasq, wp, biasp);

  // qkv GEMM (fused transpose, R8 config): grid.x = (b, ntile), grid.y = otile
  gemm_qkv<<<dim3(128, 4), 256, 0, stream>>>(x, wq, biasq, qkT, vbuf);

  dwconv_bn<<<dim3(C_, B_), 256, 0, stream>>>(
      vbuf, pe_w, pe_gamma, pe_beta, pe_mean, pe_var, posb);

  // attention: grid.x = bh (XCD affinity), grid.y = q-tile
  attn_mfma<<<dim3(128, 8), 256, 0, stream>>>(qkT, vbuf, posb, vattnT);

  // proj GEMM: grid (ntile, otile) = 512 blocks (2/CU)
  gemm_proj<<<dim3(128, 4), 256, 0, stream>>>(vattnT, wp, biasp, out);
}